// Round 1
// baseline (188.917 us; speedup 1.0000x reference)
//
#include <hip/hip_runtime.h>
#include <hip/hip_bf16.h>
#include <math.h>

#define V 4096
#define E 8192
#define HV 256
#define HE 128
#define OUT_DIM 256
#define EPS 1e-6f

// ---------------------------------------------------------------------------
// 1) Extract one-hot column indices: out[e] = v such that m[v][e] == 1
//    m viewed as float4 [V][E/4]; exactly one 1 per column -> plain write.
// ---------------------------------------------------------------------------
__global__ __launch_bounds__(256) void idx_kernel(const float4* __restrict__ m,
                                                  int* __restrict__ out) {
    const int EQ = E / 4;
    const size_t total = (size_t)V * EQ;
    for (size_t i = (size_t)blockIdx.x * blockDim.x + threadIdx.x; i < total;
         i += (size_t)gridDim.x * blockDim.x) {
        float4 x = m[i];
        if (x.x + x.y + x.z + x.w > 0.5f) {
            int v  = (int)(i / EQ);
            int c4 = (int)(i % EQ) * 4;
            if (x.x > 0.5f) out[c4 + 0] = v;
            if (x.y > 0.5f) out[c4 + 1] = v;
            if (x.z > 0.5f) out[c4 + 2] = v;
            if (x.w > 0.5f) out[c4 + 3] = v;
        }
    }
}

// ---------------------------------------------------------------------------
// 2) Attention projections: pu[v]=hv[v].wa_u, pv[v]=hv[v].wa_v, pe[e]=he[e].wa_e
//    One wave (64 lanes) per row.
// ---------------------------------------------------------------------------
__global__ __launch_bounds__(64) void proj_kernel(const float* __restrict__ hv,
                                                  const float* __restrict__ he,
                                                  const float* __restrict__ watt,
                                                  float* __restrict__ pu,
                                                  float* __restrict__ pv,
                                                  float* __restrict__ pe) {
    int r = blockIdx.x;
    int lane = threadIdx.x;
    if (r < V) {
        float4 x  = *(const float4*)(hv + (size_t)r * HV + lane * 4);
        float4 wu = *(const float4*)(watt + lane * 4);
        float4 wv = *(const float4*)(watt + HV + HE + lane * 4);
        float su = x.x * wu.x + x.y * wu.y + x.z * wu.z + x.w * wu.w;
        float sv = x.x * wv.x + x.y * wv.y + x.z * wv.z + x.w * wv.w;
        #pragma unroll
        for (int o = 32; o > 0; o >>= 1) {
            su += __shfl_down(su, o);
            sv += __shfl_down(sv, o);
        }
        if (lane == 0) { pu[r] = su; pv[r] = sv; }
    } else {
        int e = r - V;
        float2 x = *(const float2*)(he + (size_t)e * HE + lane * 2);
        float2 w = *(const float2*)(watt + HV + lane * 2);
        float s = x.x * w.x + x.y * w.y;
        #pragma unroll
        for (int o = 32; o > 0; o >>= 1) s += __shfl_down(s, o);
        if (lane == 0) pe[e] = s;
    }
}

// ---------------------------------------------------------------------------
// 3) Per-directed-edge sigmoid weight + degree accumulation (atomics).
//    e2 < E: (uu,vv) = (iu[e2], iv[e2]);  e2 >= E: (iv[e2-E], iu[e2-E])
// ---------------------------------------------------------------------------
__global__ __launch_bounds__(256) void edge_kernel(const int* __restrict__ iu,
                                                   const int* __restrict__ iv,
                                                   const float* __restrict__ pu,
                                                   const float* __restrict__ pv,
                                                   const float* __restrict__ pe,
                                                   const float* __restrict__ batt,
                                                   float* __restrict__ ew,
                                                   float* __restrict__ dr,
                                                   float* __restrict__ dc) {
    int e2 = blockIdx.x * blockDim.x + threadIdx.x;
    if (e2 >= 2 * E) return;
    int e  = (e2 < E) ? e2 : e2 - E;
    int uu = (e2 < E) ? iu[e] : iv[e];
    int vv = (e2 < E) ? iv[e] : iu[e];
    float x = pu[uu] + pe[e] + pv[vv] + batt[0];
    float w = 1.0f / (1.0f + expf(-x));
    ew[e2] = w;
    atomicAdd(dr + uu, w);
    atomicAdd(dc + vv, w);
}

// ---------------------------------------------------------------------------
// 4) Generic f32 GEMM: C[M,N] = act(maybe(C) + A[M,K]@B[K,N] + bias)
//    64x64 block tile, 256 threads, 4x4 per-thread microtile, BK=16.
//    M%64==0, N%64==0, K%16==0 assumed.
// ---------------------------------------------------------------------------
template <int ACT, int ACCUM, int BIAS>
__global__ __launch_bounds__(256) void gemm_f32(const float* __restrict__ A,
                                                const float* __restrict__ B,
                                                const float* __restrict__ bias,
                                                float* __restrict__ C,
                                                int M, int N, int K) {
    __shared__ float As[16][64];   // transposed A tile: As[k][m]
    __shared__ float Bs[16][64];   // Bs[k][n]
    const int tid = threadIdx.x;
    const int bm = blockIdx.y * 64;
    const int bn = blockIdx.x * 64;
    const int tx = tid & 15;       // col group
    const int ty = tid >> 4;       // row group
    float acc[4][4] = {};

    for (int k0 = 0; k0 < K; k0 += 16) {
        {   // load A tile 64x16 -> transposed
            int r = tid >> 2;
            int c = (tid & 3) * 4;
            float4 a = *(const float4*)(A + (size_t)(bm + r) * K + k0 + c);
            As[c + 0][r] = a.x; As[c + 1][r] = a.y;
            As[c + 2][r] = a.z; As[c + 3][r] = a.w;
        }
        {   // load B tile 16x64
            int r = tid >> 4;
            int c = (tid & 15) * 4;
            *(float4*)&Bs[r][c] = *(const float4*)(B + (size_t)(k0 + r) * N + bn + c);
        }
        __syncthreads();
        #pragma unroll
        for (int k = 0; k < 16; ++k) {
            float4 a4 = *(float4*)&As[k][ty * 4];
            float4 b4 = *(float4*)&Bs[k][tx * 4];
            acc[0][0] += a4.x * b4.x; acc[0][1] += a4.x * b4.y;
            acc[0][2] += a4.x * b4.z; acc[0][3] += a4.x * b4.w;
            acc[1][0] += a4.y * b4.x; acc[1][1] += a4.y * b4.y;
            acc[1][2] += a4.y * b4.z; acc[1][3] += a4.y * b4.w;
            acc[2][0] += a4.z * b4.x; acc[2][1] += a4.z * b4.y;
            acc[2][2] += a4.z * b4.z; acc[2][3] += a4.z * b4.w;
            acc[3][0] += a4.w * b4.x; acc[3][1] += a4.w * b4.y;
            acc[3][2] += a4.w * b4.z; acc[3][3] += a4.w * b4.w;
        }
        __syncthreads();
    }

    #pragma unroll
    for (int i = 0; i < 4; ++i) {
        int row = bm + ty * 4 + i;
        #pragma unroll
        for (int j = 0; j < 4; ++j) {
            int col = bn + tx * 4 + j;
            float v = acc[i][j];
            if (ACCUM) v += C[(size_t)row * N + col];
            if (BIAS)  v += bias[col];
            if (ACT == 1) v = (v > 0.0f) ? v : 0.01f * v;   // leaky_relu
            C[(size_t)row * N + col] = v;
        }
    }
}

// ---------------------------------------------------------------------------
// 5) Scatter: acc[uu][:] += ew[e2] * dc_rsqrt[vv] * X[vv][:]
//    One block (64 threads, float4 each) per directed edge.
// ---------------------------------------------------------------------------
__global__ __launch_bounds__(64) void scatter_kernel(const int* __restrict__ iu,
                                                     const int* __restrict__ iv,
                                                     const float* __restrict__ ew,
                                                     const float* __restrict__ dc,
                                                     const float* __restrict__ X,
                                                     float* __restrict__ acc) {
    int e2 = blockIdx.x;
    int t  = threadIdx.x;
    int e  = (e2 < E) ? e2 : e2 - E;
    int uu = (e2 < E) ? iu[e] : iv[e];
    int vv = (e2 < E) ? iv[e] : iu[e];
    float coef = ew[e2] * rsqrtf(fmaxf(dc[vv], EPS));
    float4 x = *(const float4*)(X + (size_t)vv * HV + t * 4);
    float* dst = acc + (size_t)uu * HV + t * 4;
    atomicAdd(dst + 0, coef * x.x);
    atomicAdd(dst + 1, coef * x.y);
    atomicAdd(dst + 2, coef * x.z);
    atomicAdd(dst + 3, coef * x.w);
}

// ---------------------------------------------------------------------------
// 6) Finish GCN: hidden = tanh(d_r^{-1/2}[row] * acc)   (in place)
// ---------------------------------------------------------------------------
__global__ __launch_bounds__(256) void finish_kernel(const float* __restrict__ dr,
                                                     float* __restrict__ acc) {
    const size_t total = (size_t)V * HV;
    for (size_t idx = (size_t)blockIdx.x * blockDim.x + threadIdx.x; idx < total;
         idx += (size_t)gridDim.x * blockDim.x) {
        int row = (int)(idx >> 8);   // HV = 256
        float s = rsqrtf(fmaxf(dr[row], EPS));
        acc[idx] = tanhf(s * acc[idx]);
    }
}

// ---------------------------------------------------------------------------
extern "C" void kernel_launch(void* const* d_in, const int* in_sizes, int n_in,
                              void* d_out, int out_size, void* d_ws, size_t ws_size,
                              hipStream_t stream) {
    const float* hv   = (const float*)d_in[0];
    const float* he   = (const float*)d_in[1];
    const float* vew1 = (const float*)d_in[2];
    const float* vew2 = (const float*)d_in[3];
    const float* watt = (const float*)d_in[4];
    const float* batt = (const float*)d_in[5];
    const float* wgcn = (const float*)d_in[6];
    const float* bgcn = (const float*)d_in[7];
    const float* w1   = (const float*)d_in[8];
    const float* b1   = (const float*)d_in[9];
    const float* w2   = (const float*)d_in[10];
    const float* b2   = (const float*)d_in[11];
    float* out = (float*)d_out;

    // workspace layout (4-byte words)
    float* ws = (float*)d_ws;
    int*   iu  = (int*)ws;                       // E
    int*   iv  = (int*)(ws + E);                 // E
    float* pu  = ws + 2 * E;                     // V
    float* pv  = pu + V;                         // V
    float* pe  = pv + V;                         // E
    float* ew  = pe + E;                         // 2E
    float* dr  = ew + 2 * E;                     // V      (zeroed)
    float* dc  = dr + V;                         // V      (zeroed)
    float* acc = dc + V;                         // V*HV   (zeroed) -> hidden
    float* X   = acc + (size_t)V * HV;           // V*HV   -> later reused as t

    // zero accumulators (dr, dc, acc are contiguous)
    hipMemsetAsync(dr, 0, (size_t)(2 * V + V * HV) * sizeof(float), stream);

    // index extraction (the 256 MB scan)
    idx_kernel<<<2048, 256, 0, stream>>>((const float4*)vew1, iu);
    idx_kernel<<<2048, 256, 0, stream>>>((const float4*)vew2, iv);

    // attention projections
    proj_kernel<<<V + E, 64, 0, stream>>>(hv, he, watt, pu, pv, pe);

    // edge weights + degrees
    edge_kernel<<<(2 * E + 255) / 256, 256, 0, stream>>>(iu, iv, pu, pv, pe, batt, ew, dr, dc);

    // X = hv @ w_gcn + b_gcn
    gemm_f32<0, 0, 1><<<dim3(HV / 64, V / 64), 256, 0, stream>>>(hv, wgcn, bgcn, X, V, HV, HV);

    // acc[uu] += ew * dc^{-1/2}[vv] * X[vv]
    scatter_kernel<<<2 * E, 64, 0, stream>>>(iu, iv, ew, dc, X, acc);

    // hidden = tanh(dr^{-1/2} * acc)  (in place)
    finish_kernel<<<1024, 256, 0, stream>>>(dr, acc);

    // MLP with split-K for the [hv, hidden] concat:
    // t = hv @ w1[0:HV,:]             (raw)
    gemm_f32<0, 0, 0><<<dim3(HV / 64, V / 64), 256, 0, stream>>>(hv, w1, nullptr, X, V, HV, HV);
    // t = leaky_relu(t + hidden @ w1[HV:2HV,:] + b1)
    gemm_f32<1, 1, 1><<<dim3(HV / 64, V / 64), 256, 0, stream>>>(acc, w1 + (size_t)HV * HV, b1, X, V, HV, HV);
    // out = t @ w2 + b2
    gemm_f32<0, 0, 1><<<dim3(OUT_DIM / 64, V / 64), 256, 0, stream>>>(X, w2, b2, out, V, OUT_DIM, HV);
}

// Round 2
// 188.477 us; speedup vs baseline: 1.0023x; 1.0023x over previous
//
#include <hip/hip_runtime.h>
#include <hip/hip_bf16.h>
#include <math.h>

#define V 4096
#define E 8192
#define HV 256
#define HE 128
#define OUT_DIM 256
#define EPS 1e-6f

// ---------------------------------------------------------------------------
// 0) Fast zero-fill (the runtime's fillBufferAligned runs at 55 GB/s for
//    small fills -- 77us for 4MB. This does it in ~1-2us.)
//    n4 = number of float4 elements.
// ---------------------------------------------------------------------------
__global__ __launch_bounds__(256) void zero_kernel(float4* __restrict__ p, int n4) {
    int i = blockIdx.x * blockDim.x + threadIdx.x;
    int stride = gridDim.x * blockDim.x;
    float4 z = {0.0f, 0.0f, 0.0f, 0.0f};
    for (; i < n4; i += stride) p[i] = z;
}

// ---------------------------------------------------------------------------
// 1) Extract one-hot column indices: out[e] = v such that m[v][e] == 1
//    m viewed as float4 [V][E/4]; exactly one 1 per column -> plain write.
// ---------------------------------------------------------------------------
__global__ __launch_bounds__(256) void idx_kernel(const float4* __restrict__ m,
                                                  int* __restrict__ out) {
    const int EQ = E / 4;
    const size_t total = (size_t)V * EQ;
    for (size_t i = (size_t)blockIdx.x * blockDim.x + threadIdx.x; i < total;
         i += (size_t)gridDim.x * blockDim.x) {
        float4 x = m[i];
        if (x.x + x.y + x.z + x.w > 0.5f) {
            int v  = (int)(i / EQ);
            int c4 = (int)(i % EQ) * 4;
            if (x.x > 0.5f) out[c4 + 0] = v;
            if (x.y > 0.5f) out[c4 + 1] = v;
            if (x.z > 0.5f) out[c4 + 2] = v;
            if (x.w > 0.5f) out[c4 + 3] = v;
        }
    }
}

// ---------------------------------------------------------------------------
// 2) Attention projections: pu[v]=hv[v].wa_u, pv[v]=hv[v].wa_v, pe[e]=he[e].wa_e
//    One wave (64 lanes) per row.
// ---------------------------------------------------------------------------
__global__ __launch_bounds__(64) void proj_kernel(const float* __restrict__ hv,
                                                  const float* __restrict__ he,
                                                  const float* __restrict__ watt,
                                                  float* __restrict__ pu,
                                                  float* __restrict__ pv,
                                                  float* __restrict__ pe) {
    int r = blockIdx.x;
    int lane = threadIdx.x;
    if (r < V) {
        float4 x  = *(const float4*)(hv + (size_t)r * HV + lane * 4);
        float4 wu = *(const float4*)(watt + lane * 4);
        float4 wv = *(const float4*)(watt + HV + HE + lane * 4);
        float su = x.x * wu.x + x.y * wu.y + x.z * wu.z + x.w * wu.w;
        float sv = x.x * wv.x + x.y * wv.y + x.z * wv.z + x.w * wv.w;
        #pragma unroll
        for (int o = 32; o > 0; o >>= 1) {
            su += __shfl_down(su, o);
            sv += __shfl_down(sv, o);
        }
        if (lane == 0) { pu[r] = su; pv[r] = sv; }
    } else {
        int e = r - V;
        float2 x = *(const float2*)(he + (size_t)e * HE + lane * 2);
        float2 w = *(const float2*)(watt + HV + lane * 2);
        float s = x.x * w.x + x.y * w.y;
        #pragma unroll
        for (int o = 32; o > 0; o >>= 1) s += __shfl_down(s, o);
        if (lane == 0) pe[e] = s;
    }
}

// ---------------------------------------------------------------------------
// 3) Per-directed-edge sigmoid weight + degree accumulation (atomics).
// ---------------------------------------------------------------------------
__global__ __launch_bounds__(256) void edge_kernel(const int* __restrict__ iu,
                                                   const int* __restrict__ iv,
                                                   const float* __restrict__ pu,
                                                   const float* __restrict__ pv,
                                                   const float* __restrict__ pe,
                                                   const float* __restrict__ batt,
                                                   float* __restrict__ ew,
                                                   float* __restrict__ dr,
                                                   float* __restrict__ dc) {
    int e2 = blockIdx.x * blockDim.x + threadIdx.x;
    if (e2 >= 2 * E) return;
    int e  = (e2 < E) ? e2 : e2 - E;
    int uu = (e2 < E) ? iu[e] : iv[e];
    int vv = (e2 < E) ? iv[e] : iu[e];
    float x = pu[uu] + pe[e] + pv[vv] + batt[0];
    float w = 1.0f / (1.0f + expf(-x));
    ew[e2] = w;
    atomicAdd(dr + uu, w);
    atomicAdd(dc + vv, w);
}

// ---------------------------------------------------------------------------
// 4) Generic f32 GEMM: C[M,N] = act(maybe(C) + A[M,K]@B[K,N] + bias)
//    64x64 block tile, 256 threads, 4x4 per-thread microtile, BK=16.
// ---------------------------------------------------------------------------
template <int ACT, int ACCUM, int BIAS>
__global__ __launch_bounds__(256) void gemm_f32(const float* __restrict__ A,
                                                const float* __restrict__ B,
                                                const float* __restrict__ bias,
                                                float* __restrict__ C,
                                                int M, int N, int K) {
    __shared__ float As[16][64];   // transposed A tile: As[k][m]
    __shared__ float Bs[16][64];   // Bs[k][n]
    const int tid = threadIdx.x;
    const int bm = blockIdx.y * 64;
    const int bn = blockIdx.x * 64;
    const int tx = tid & 15;
    const int ty = tid >> 4;
    float acc[4][4] = {};

    for (int k0 = 0; k0 < K; k0 += 16) {
        {
            int r = tid >> 2;
            int c = (tid & 3) * 4;
            float4 a = *(const float4*)(A + (size_t)(bm + r) * K + k0 + c);
            As[c + 0][r] = a.x; As[c + 1][r] = a.y;
            As[c + 2][r] = a.z; As[c + 3][r] = a.w;
        }
        {
            int r = tid >> 4;
            int c = (tid & 15) * 4;
            *(float4*)&Bs[r][c] = *(const float4*)(B + (size_t)(k0 + r) * N + bn + c);
        }
        __syncthreads();
        #pragma unroll
        for (int k = 0; k < 16; ++k) {
            float4 a4 = *(float4*)&As[k][ty * 4];
            float4 b4 = *(float4*)&Bs[k][tx * 4];
            acc[0][0] += a4.x * b4.x; acc[0][1] += a4.x * b4.y;
            acc[0][2] += a4.x * b4.z; acc[0][3] += a4.x * b4.w;
            acc[1][0] += a4.y * b4.x; acc[1][1] += a4.y * b4.y;
            acc[1][2] += a4.y * b4.z; acc[1][3] += a4.y * b4.w;
            acc[2][0] += a4.z * b4.x; acc[2][1] += a4.z * b4.y;
            acc[2][2] += a4.z * b4.z; acc[2][3] += a4.z * b4.w;
            acc[3][0] += a4.w * b4.x; acc[3][1] += a4.w * b4.y;
            acc[3][2] += a4.w * b4.z; acc[3][3] += a4.w * b4.w;
        }
        __syncthreads();
    }

    #pragma unroll
    for (int i = 0; i < 4; ++i) {
        int row = bm + ty * 4 + i;
        #pragma unroll
        for (int j = 0; j < 4; ++j) {
            int col = bn + tx * 4 + j;
            float v = acc[i][j];
            if (ACCUM) v += C[(size_t)row * N + col];
            if (BIAS)  v += bias[col];
            if (ACT == 1) v = (v > 0.0f) ? v : 0.01f * v;   // leaky_relu
            C[(size_t)row * N + col] = v;
        }
    }
}

// ---------------------------------------------------------------------------
// 5) Scatter: acc[uu][:] += ew[e2] * dc_rsqrt[vv] * X[vv][:]
// ---------------------------------------------------------------------------
__global__ __launch_bounds__(64) void scatter_kernel(const int* __restrict__ iu,
                                                     const int* __restrict__ iv,
                                                     const float* __restrict__ ew,
                                                     const float* __restrict__ dc,
                                                     const float* __restrict__ X,
                                                     float* __restrict__ acc) {
    int e2 = blockIdx.x;
    int t  = threadIdx.x;
    int e  = (e2 < E) ? e2 : e2 - E;
    int uu = (e2 < E) ? iu[e] : iv[e];
    int vv = (e2 < E) ? iv[e] : iu[e];
    float coef = ew[e2] * rsqrtf(fmaxf(dc[vv], EPS));
    float4 x = *(const float4*)(X + (size_t)vv * HV + t * 4);
    float* dst = acc + (size_t)uu * HV + t * 4;
    atomicAdd(dst + 0, coef * x.x);
    atomicAdd(dst + 1, coef * x.y);
    atomicAdd(dst + 2, coef * x.z);
    atomicAdd(dst + 3, coef * x.w);
}

// ---------------------------------------------------------------------------
// 6) Finish GCN: hidden = tanh(d_r^{-1/2}[row] * acc)   (in place)
// ---------------------------------------------------------------------------
__global__ __launch_bounds__(256) void finish_kernel(const float* __restrict__ dr,
                                                     float* __restrict__ acc) {
    const size_t total = (size_t)V * HV;
    for (size_t idx = (size_t)blockIdx.x * blockDim.x + threadIdx.x; idx < total;
         idx += (size_t)gridDim.x * blockDim.x) {
        int row = (int)(idx >> 8);   // HV = 256
        float s = rsqrtf(fmaxf(dr[row], EPS));
        acc[idx] = tanhf(s * acc[idx]);
    }
}

// ---------------------------------------------------------------------------
extern "C" void kernel_launch(void* const* d_in, const int* in_sizes, int n_in,
                              void* d_out, int out_size, void* d_ws, size_t ws_size,
                              hipStream_t stream) {
    const float* hv   = (const float*)d_in[0];
    const float* he   = (const float*)d_in[1];
    const float* vew1 = (const float*)d_in[2];
    const float* vew2 = (const float*)d_in[3];
    const float* watt = (const float*)d_in[4];
    const float* batt = (const float*)d_in[5];
    const float* wgcn = (const float*)d_in[6];
    const float* bgcn = (const float*)d_in[7];
    const float* w1   = (const float*)d_in[8];
    const float* b1   = (const float*)d_in[9];
    const float* w2   = (const float*)d_in[10];
    const float* b2   = (const float*)d_in[11];
    float* out = (float*)d_out;

    // workspace layout (4-byte words)
    float* ws = (float*)d_ws;
    int*   iu  = (int*)ws;                       // E
    int*   iv  = (int*)(ws + E);                 // E
    float* pu  = ws + 2 * E;                     // V
    float* pv  = pu + V;                         // V
    float* pe  = pv + V;                         // E
    float* ew  = pe + E;                         // 2E
    float* dr  = ew + 2 * E;                     // V      (zeroed)
    float* dc  = dr + V;                         // V      (zeroed)
    float* acc = dc + V;                         // V*HV   (zeroed) -> hidden
    float* X   = acc + (size_t)V * HV;           // V*HV   -> later reused as t

    // zero accumulators with our own kernel (runtime fill kernel = 55 GB/s, 77us)
    {
        int n4 = (2 * V + V * HV) / 4;   // dr,dc,acc contiguous
        zero_kernel<<<1024, 256, 0, stream>>>((float4*)dr, n4);
    }

    // index extraction (the 256 MB scan)
    idx_kernel<<<2048, 256, 0, stream>>>((const float4*)vew1, iu);
    idx_kernel<<<2048, 256, 0, stream>>>((const float4*)vew2, iv);

    // attention projections
    proj_kernel<<<V + E, 64, 0, stream>>>(hv, he, watt, pu, pv, pe);

    // edge weights + degrees
    edge_kernel<<<(2 * E + 255) / 256, 256, 0, stream>>>(iu, iv, pu, pv, pe, batt, ew, dr, dc);

    // X = hv @ w_gcn + b_gcn
    gemm_f32<0, 0, 1><<<dim3(HV / 64, V / 64), 256, 0, stream>>>(hv, wgcn, bgcn, X, V, HV, HV);

    // acc[uu] += ew * dc^{-1/2}[vv] * X[vv]
    scatter_kernel<<<2 * E, 64, 0, stream>>>(iu, iv, ew, dc, X, acc);

    // hidden = tanh(dr^{-1/2} * acc)  (in place)
    finish_kernel<<<1024, 256, 0, stream>>>(dr, acc);

    // MLP with split-K for the [hv, hidden] concat:
    gemm_f32<0, 0, 0><<<dim3(HV / 64, V / 64), 256, 0, stream>>>(hv, w1, nullptr, X, V, HV, HV);
    gemm_f32<1, 1, 1><<<dim3(HV / 64, V / 64), 256, 0, stream>>>(acc, w1 + (size_t)HV * HV, b1, X, V, HV, HV);
    gemm_f32<0, 0, 1><<<dim3(OUT_DIM / 64, V / 64), 256, 0, stream>>>(X, w2, b2, out, V, OUT_DIM, HV);
}

// Round 3
// 150.874 us; speedup vs baseline: 1.2521x; 1.2492x over previous
//
#include <hip/hip_runtime.h>
#include <hip/hip_bf16.h>
#include <math.h>

#define V 4096
#define E 8192
#define HV 256
#define HE 128
#define OUT_DIM 256
#define EPS 1e-6f

typedef __attribute__((ext_vector_type(8))) short short8;
typedef __attribute__((ext_vector_type(4))) float f32x4;

__device__ __forceinline__ unsigned short f2bf(float f) {
    __hip_bfloat16 h = __float2bfloat16(f);
    return *(unsigned short*)&h;
}

// ---------------------------------------------------------------------------
// 0) Fast zero-fill. n4 = number of float4 elements.
// ---------------------------------------------------------------------------
__global__ __launch_bounds__(256) void zero_kernel(float4* __restrict__ p, int n4) {
    int i = blockIdx.x * blockDim.x + threadIdx.x;
    int stride = gridDim.x * blockDim.x;
    float4 z = {0.0f, 0.0f, 0.0f, 0.0f};
    for (; i < n4; i += stride) p[i] = z;
}

// ---------------------------------------------------------------------------
// 1) Extract one-hot column indices: out[e] = v such that m[v][e] == 1
// ---------------------------------------------------------------------------
__global__ __launch_bounds__(256) void idx_kernel(const float4* __restrict__ m,
                                                  int* __restrict__ out) {
    const int EQ = E / 4;
    const size_t total = (size_t)V * EQ;
    for (size_t i = (size_t)blockIdx.x * blockDim.x + threadIdx.x; i < total;
         i += (size_t)gridDim.x * blockDim.x) {
        float4 x = m[i];
        if (x.x + x.y + x.z + x.w > 0.5f) {
            int v  = (int)(i / EQ);
            int c4 = (int)(i % EQ) * 4;
            if (x.x > 0.5f) out[c4 + 0] = v;
            if (x.y > 0.5f) out[c4 + 1] = v;
            if (x.z > 0.5f) out[c4 + 2] = v;
            if (x.w > 0.5f) out[c4 + 3] = v;
        }
    }
}

// ---------------------------------------------------------------------------
// 2) f32 -> bf16 elementwise convert (vectorized by 4)
// ---------------------------------------------------------------------------
__global__ __launch_bounds__(256) void conv_kernel(const float4* __restrict__ src,
                                                   ushort4* __restrict__ dst, int n4) {
    int i = blockIdx.x * blockDim.x + threadIdx.x;
    int stride = gridDim.x * blockDim.x;
    for (; i < n4; i += stride) {
        float4 x = src[i];
        ushort4 o;
        o.x = f2bf(x.x); o.y = f2bf(x.y); o.z = f2bf(x.z); o.w = f2bf(x.w);
        dst[i] = o;
    }
}

// ---------------------------------------------------------------------------
// 3) f32 [K][N] -> bf16 [N][K] transpose-convert (for weights)
// ---------------------------------------------------------------------------
__global__ __launch_bounds__(256) void convT_kernel(const float* __restrict__ src,
                                                    unsigned short* __restrict__ dst,
                                                    int K, int N) {
    int i = blockIdx.x * blockDim.x + threadIdx.x;
    if (i >= N * K) return;
    int n = i / K, k = i - n * K;
    dst[i] = f2bf(src[(size_t)k * N + n]);
}

// ---------------------------------------------------------------------------
// 4) Attention projections (one wave per row)
// ---------------------------------------------------------------------------
__global__ __launch_bounds__(64) void proj_kernel(const float* __restrict__ hv,
                                                  const float* __restrict__ he,
                                                  const float* __restrict__ watt,
                                                  float* __restrict__ pu,
                                                  float* __restrict__ pv,
                                                  float* __restrict__ pe) {
    int r = blockIdx.x;
    int lane = threadIdx.x;
    if (r < V) {
        float4 x  = *(const float4*)(hv + (size_t)r * HV + lane * 4);
        float4 wu = *(const float4*)(watt + lane * 4);
        float4 wv = *(const float4*)(watt + HV + HE + lane * 4);
        float su = x.x * wu.x + x.y * wu.y + x.z * wu.z + x.w * wu.w;
        float sv = x.x * wv.x + x.y * wv.y + x.z * wv.z + x.w * wv.w;
        #pragma unroll
        for (int o = 32; o > 0; o >>= 1) {
            su += __shfl_down(su, o);
            sv += __shfl_down(sv, o);
        }
        if (lane == 0) { pu[r] = su; pv[r] = sv; }
    } else {
        int e = r - V;
        float2 x = *(const float2*)(he + (size_t)e * HE + lane * 2);
        float2 w = *(const float2*)(watt + HV + lane * 2);
        float s = x.x * w.x + x.y * w.y;
        #pragma unroll
        for (int o = 32; o > 0; o >>= 1) s += __shfl_down(s, o);
        if (lane == 0) pe[e] = s;
    }
}

// ---------------------------------------------------------------------------
// 5) Per-directed-edge sigmoid weight + degree accumulation
// ---------------------------------------------------------------------------
__global__ __launch_bounds__(256) void edge_kernel(const int* __restrict__ iu,
                                                   const int* __restrict__ iv,
                                                   const float* __restrict__ pu,
                                                   const float* __restrict__ pv,
                                                   const float* __restrict__ pe,
                                                   const float* __restrict__ batt,
                                                   float* __restrict__ ew,
                                                   float* __restrict__ dr,
                                                   float* __restrict__ dc) {
    int e2 = blockIdx.x * blockDim.x + threadIdx.x;
    if (e2 >= 2 * E) return;
    int e  = (e2 < E) ? e2 : e2 - E;
    int uu = (e2 < E) ? iu[e] : iv[e];
    int vv = (e2 < E) ? iv[e] : iu[e];
    float x = pu[uu] + pe[e] + pv[vv] + batt[0];
    float w = 1.0f / (1.0f + expf(-x));
    ew[e2] = w;
    atomicAdd(dr + uu, w);
    atomicAdd(dc + vv, w);
}

// ---------------------------------------------------------------------------
// 6) bf16 MFMA GEMM: C[M,N] = act(Acat[M,Ktot] @ BT^T + bias)
//    Acat = [A0 | A1] (row stride KSEG each, NSEG segments), BT is [N][Ktot] bf16.
//    64x64 block tile, 4 waves (2x2 of 32x32), BK=32, 16x16x32 MFMA.
//    Fragment layout: A row = lane&15, k = (lane>>4)*8+j (contig);
//                     B (from BT rows) col = lane&15, same k pattern;
//                     C/D col = lane&15, row = (lane>>4)*4 + reg.
// ---------------------------------------------------------------------------
template <int ACT, int OBF>
__global__ __launch_bounds__(256) void gemm_bf16(const unsigned short* __restrict__ A0,
                                                 const unsigned short* __restrict__ A1,
                                                 int KSEG, int NSEG,
                                                 const unsigned short* __restrict__ BT,
                                                 const float* __restrict__ bias,
                                                 void* __restrict__ Cout,
                                                 int M, int N) {
    __shared__ __align__(16) unsigned short As[64 * 40];   // padded: 40 ushorts/row
    __shared__ __align__(16) unsigned short Bs[64 * 40];
    const int tid  = threadIdx.x;
    const int lane = tid & 63;
    const int w    = tid >> 6;
    const int wm   = w >> 1, wn = w & 1;
    const int bm   = blockIdx.y * 64, bn = blockIdx.x * 64;
    const int Ktot = KSEG * NSEG;

    const int sr = tid >> 2;            // staging row 0..63
    const int sc = (tid & 3) * 8;       // staging k-offset {0,8,16,24}
    const int fr = lane & 15;
    const int kc = (lane >> 4) * 8;

    f32x4 acc[2][2] = {};

    for (int k0 = 0; k0 < Ktot; k0 += 32) {
        int seg = (k0 >= KSEG) ? 1 : 0;
        int kk  = k0 - seg * KSEG;
        const unsigned short* Asrc = seg ? A1 : A0;
        *(short8*)&As[sr * 40 + sc] = *(const short8*)&Asrc[(size_t)(bm + sr) * KSEG + kk + sc];
        *(short8*)&Bs[sr * 40 + sc] = *(const short8*)&BT[(size_t)(bn + sr) * Ktot + k0 + sc];
        __syncthreads();
        short8 bfr[2];
        bfr[0] = *(const short8*)&Bs[(wn * 32 + 0 * 16 + fr) * 40 + kc];
        bfr[1] = *(const short8*)&Bs[(wn * 32 + 1 * 16 + fr) * 40 + kc];
        #pragma unroll
        for (int ms = 0; ms < 2; ++ms) {
            short8 af = *(const short8*)&As[(wm * 32 + ms * 16 + fr) * 40 + kc];
            acc[ms][0] = __builtin_amdgcn_mfma_f32_16x16x32_bf16(af, bfr[0], acc[ms][0], 0, 0, 0);
            acc[ms][1] = __builtin_amdgcn_mfma_f32_16x16x32_bf16(af, bfr[1], acc[ms][1], 0, 0, 0);
        }
        __syncthreads();
    }

    #pragma unroll
    for (int ms = 0; ms < 2; ++ms) {
        #pragma unroll
        for (int ns = 0; ns < 2; ++ns) {
            int col = bn + wn * 32 + ns * 16 + fr;
            float bv = bias ? bias[col] : 0.0f;
            #pragma unroll
            for (int r = 0; r < 4; ++r) {
                int row = bm + wm * 32 + ms * 16 + ((lane >> 4) << 2) + r;
                float v = acc[ms][ns][r] + bv;
                if (ACT == 1) v = (v > 0.0f) ? v : 0.01f * v;   // leaky_relu
                if (OBF) ((unsigned short*)Cout)[(size_t)row * N + col] = f2bf(v);
                else     ((float*)Cout)[(size_t)row * N + col] = v;
            }
        }
    }
}

// ---------------------------------------------------------------------------
// 7) Scatter: acc[uu][:] += ew[e2] * dc^{-1/2}[vv] * X[vv][:]
// ---------------------------------------------------------------------------
__global__ __launch_bounds__(64) void scatter_kernel(const int* __restrict__ iu,
                                                     const int* __restrict__ iv,
                                                     const float* __restrict__ ew,
                                                     const float* __restrict__ dc,
                                                     const float* __restrict__ X,
                                                     float* __restrict__ acc) {
    int e2 = blockIdx.x;
    int t  = threadIdx.x;
    int e  = (e2 < E) ? e2 : e2 - E;
    int uu = (e2 < E) ? iu[e] : iv[e];
    int vv = (e2 < E) ? iv[e] : iu[e];
    float coef = ew[e2] * rsqrtf(fmaxf(dc[vv], EPS));
    float4 x = *(const float4*)(X + (size_t)vv * HV + t * 4);
    float* dst = acc + (size_t)uu * HV + t * 4;
    atomicAdd(dst + 0, coef * x.x);
    atomicAdd(dst + 1, coef * x.y);
    atomicAdd(dst + 2, coef * x.z);
    atomicAdd(dst + 3, coef * x.w);
}

// ---------------------------------------------------------------------------
// 8) Finish GCN: hid16 = bf16(tanh(d_r^{-1/2}[row] * acc))
// ---------------------------------------------------------------------------
__global__ __launch_bounds__(256) void finish_kernel(const float* __restrict__ dr,
                                                     const float* __restrict__ acc,
                                                     unsigned short* __restrict__ hid16) {
    const size_t total = (size_t)V * HV;
    for (size_t idx = (size_t)blockIdx.x * blockDim.x + threadIdx.x; idx < total;
         idx += (size_t)gridDim.x * blockDim.x) {
        int row = (int)(idx >> 8);   // HV = 256
        float s = rsqrtf(fmaxf(dr[row], EPS));
        hid16[idx] = f2bf(tanhf(s * acc[idx]));
    }
}

// ---------------------------------------------------------------------------
extern "C" void kernel_launch(void* const* d_in, const int* in_sizes, int n_in,
                              void* d_out, int out_size, void* d_ws, size_t ws_size,
                              hipStream_t stream) {
    const float* hv   = (const float*)d_in[0];
    const float* he   = (const float*)d_in[1];
    const float* vew1 = (const float*)d_in[2];
    const float* vew2 = (const float*)d_in[3];
    const float* watt = (const float*)d_in[4];
    const float* batt = (const float*)d_in[5];
    const float* wgcn = (const float*)d_in[6];
    const float* bgcn = (const float*)d_in[7];
    const float* w1   = (const float*)d_in[8];
    const float* b1   = (const float*)d_in[9];
    const float* w2   = (const float*)d_in[10];
    const float* b2   = (const float*)d_in[11];
    float* out = (float*)d_out;

    // workspace layout (float words, then ushort region)
    float* ws = (float*)d_ws;
    int*   iu  = (int*)ws;                       // E
    int*   iv  = (int*)(ws + E);                 // E
    float* pu  = ws + 2 * E;                     // V
    float* pv  = pu + V;                         // V
    float* pe  = pv + V;                         // E
    float* ew  = pe + E;                         // 2E
    float* dr  = ew + 2 * E;                     // V      (zeroed)
    float* dc  = dr + V;                         // V      (zeroed)
    float* acc = dc + V;                         // V*HV   (zeroed)
    float* X   = acc + (size_t)V * HV;           // V*HV   f32 (GCN linear out)
    unsigned short* hv16  = (unsigned short*)(X + (size_t)V * HV);  // V*HV bf16
    unsigned short* hid16 = hv16 + (size_t)V * HV;                  // V*HV
    unsigned short* t16   = hid16 + (size_t)V * HV;                 // V*HV
    unsigned short* wgcnT = t16 + (size_t)V * HV;                   // HV*HV
    unsigned short* w1T   = wgcnT + HV * HV;                        // HV*2HV
    unsigned short* w2T   = w1T + 2 * HV * HV;                      // HV*OUT

    // zero accumulators (dr, dc, acc contiguous)
    zero_kernel<<<1024, 256, 0, stream>>>((float4*)dr, (2 * V + V * HV) / 4);

    // index extraction (the 256 MB scan -- structural HBM floor ~42us)
    idx_kernel<<<2048, 256, 0, stream>>>((const float4*)vew1, iu);
    idx_kernel<<<2048, 256, 0, stream>>>((const float4*)vew2, iv);

    // bf16 conversions
    conv_kernel<<<512, 256, 0, stream>>>((const float4*)hv, (ushort4*)hv16, V * HV / 4);
    convT_kernel<<<(HV * HV + 255) / 256, 256, 0, stream>>>(wgcn, wgcnT, HV, HV);
    convT_kernel<<<(2 * HV * HV + 255) / 256, 256, 0, stream>>>(w1, w1T, 2 * HV, HV);
    convT_kernel<<<(HV * OUT_DIM + 255) / 256, 256, 0, stream>>>(w2, w2T, HV, OUT_DIM);

    // attention projections + edge weights + degrees
    proj_kernel<<<V + E, 64, 0, stream>>>(hv, he, watt, pu, pv, pe);
    edge_kernel<<<(2 * E + 255) / 256, 256, 0, stream>>>(iu, iv, pu, pv, pe, batt, ew, dr, dc);

    // X = hv @ w_gcn + b_gcn   (f32 out, consumed by scatter)
    gemm_bf16<0, 0><<<dim3(HV / 64, V / 64), 256, 0, stream>>>(hv16, hv16, HV, 1, wgcnT, bgcn, X, V, HV);

    // acc[uu] += ew * dc^{-1/2}[vv] * X[vv]
    scatter_kernel<<<2 * E, 64, 0, stream>>>(iu, iv, ew, dc, X, acc);

    // hid16 = bf16(tanh(dr^{-1/2} * acc))
    finish_kernel<<<1024, 256, 0, stream>>>(dr, acc, hid16);

    // t16 = bf16(leaky_relu([hv | hidden] @ w1 + b1))   (K=512, two A segments)
    gemm_bf16<1, 1><<<dim3(HV / 64, V / 64), 256, 0, stream>>>(hv16, hid16, HV, 2, w1T, b1, t16, V, HV);

    // out = t @ w2 + b2   (f32 out)
    gemm_bf16<0, 0><<<dim3(OUT_DIM / 64, V / 64), 256, 0, stream>>>(t16, t16, HV, 1, w2T, b2, out, V, OUT_DIM);
}

// Round 4
// 135.595 us; speedup vs baseline: 1.3932x; 1.1127x over previous
//
#include <hip/hip_runtime.h>
#include <hip/hip_bf16.h>
#include <math.h>

#define V 4096
#define E 8192
#define HV 256
#define HE 128
#define OUT_DIM 256
#define EPS 1e-6f

// mega-kernel block ranges (level-1 of the dependency DAG)
#define G_GEMM1 256
#define G_PROJ  512
#define G_ZERO  64
#define G_IDX   8192   /* 4096 per incidence matrix, one-shot blocks */
#define G_TOTAL (G_GEMM1 + G_PROJ + G_ZERO + G_IDX)

typedef __attribute__((ext_vector_type(8))) short short8;
typedef __attribute__((ext_vector_type(4))) float f32x4;

__device__ __forceinline__ unsigned short f2bf(float f) {
    __hip_bfloat16 h = __float2bfloat16(f);
    return *(unsigned short*)&h;
}

__device__ __forceinline__ short8 cvt8(float4 a, float4 b) {
    short8 r;
    r[0] = f2bf(a.x); r[1] = f2bf(a.y); r[2] = f2bf(a.z); r[3] = f2bf(a.w);
    r[4] = f2bf(b.x); r[5] = f2bf(b.y); r[6] = f2bf(b.z); r[7] = f2bf(b.w);
    return r;
}

// ---------------------------------------------------------------------------
// bf16-MFMA GEMM body, f32 inputs converted during staging.
//   C[M,N] = act(Acat[M,Ktot] @ B + bias),  Acat = [A0 | A1] row stride KSEG.
//   B is f32 [Ktot][N] row-major (transposed into LDS during staging).
//   64x64 tile, 4 waves (2x2 of 32x32), BK=32, mfma_f32_16x16x32_bf16.
//   Layout verified in rounds 2-3 (absmax 1.6e-2 passing).
// ---------------------------------------------------------------------------
template <int ACT>
__device__ __forceinline__ void gemm_body(const float* __restrict__ A0,
                                          const float* __restrict__ A1,
                                          int KSEG, int NSEG,
                                          const float* __restrict__ B,
                                          const float* __restrict__ bias,
                                          float* __restrict__ Cout,
                                          int N, int bm, int bn) {
    __shared__ __align__(16) unsigned short As[64 * 40];   // [row][k] padded
    __shared__ __align__(16) unsigned short Bs[64 * 40];   // [col][k] padded
    const int tid  = threadIdx.x;
    const int lane = tid & 63;
    const int w    = tid >> 6;
    const int wm   = w >> 1, wn = w & 1;
    const int Ktot = KSEG * NSEG;

    const int sr  = tid >> 2;          // A staging row 0..63
    const int sc8 = (tid & 3) * 8;     // A staging k-offset {0,8,16,24}
    const int kb  = tid & 31;          // B staging k 0..31
    const int bc0 = (tid >> 5) * 8;    // B staging col group {0,8,...,56}
    const int fr  = lane & 15;
    const int kc  = (lane >> 4) * 8;

    f32x4 acc[2][2] = {};

    for (int k0 = 0; k0 < Ktot; k0 += 32) {
        const float* Asrc = (k0 >= KSEG) ? A1 : A0;
        int kk = (k0 >= KSEG) ? (k0 - KSEG) : k0;
        const float* ap = &Asrc[(size_t)(bm + sr) * KSEG + kk + sc8];
        float4 a0 = *(const float4*)ap;
        float4 a1 = *(const float4*)(ap + 4);
        const float* bp = &B[(size_t)(k0 + kb) * N + bn + bc0];
        float4 b0 = *(const float4*)bp;
        float4 b1 = *(const float4*)(bp + 4);
        *(short8*)&As[sr * 40 + sc8] = cvt8(a0, a1);
        unsigned short bw[8];
        bw[0] = f2bf(b0.x); bw[1] = f2bf(b0.y); bw[2] = f2bf(b0.z); bw[3] = f2bf(b0.w);
        bw[4] = f2bf(b1.x); bw[5] = f2bf(b1.y); bw[6] = f2bf(b1.z); bw[7] = f2bf(b1.w);
        #pragma unroll
        for (int j = 0; j < 8; ++j) Bs[(bc0 + j) * 40 + kb] = bw[j];
        __syncthreads();

        short8 bfr[2];
        bfr[0] = *(const short8*)&Bs[(wn * 32 + 0 * 16 + fr) * 40 + kc];
        bfr[1] = *(const short8*)&Bs[(wn * 32 + 1 * 16 + fr) * 40 + kc];
        #pragma unroll
        for (int ms = 0; ms < 2; ++ms) {
            short8 af = *(const short8*)&As[(wm * 32 + ms * 16 + fr) * 40 + kc];
            acc[ms][0] = __builtin_amdgcn_mfma_f32_16x16x32_bf16(af, bfr[0], acc[ms][0], 0, 0, 0);
            acc[ms][1] = __builtin_amdgcn_mfma_f32_16x16x32_bf16(af, bfr[1], acc[ms][1], 0, 0, 0);
        }
        __syncthreads();
    }

    #pragma unroll
    for (int ms = 0; ms < 2; ++ms) {
        #pragma unroll
        for (int ns = 0; ns < 2; ++ns) {
            int col = bn + wn * 32 + ns * 16 + fr;
            float bv = bias ? bias[col] : 0.0f;
            #pragma unroll
            for (int r = 0; r < 4; ++r) {
                int row = bm + wm * 32 + ms * 16 + ((lane >> 4) << 2) + r;
                float v = acc[ms][ns][r] + bv;
                if (ACT == 1) v = (v > 0.0f) ? v : 0.01f * v;   // leaky_relu
                Cout[(size_t)row * N + col] = v;
            }
        }
    }
}

template <int ACT>
__global__ __launch_bounds__(256) void gemm_kernel(const float* __restrict__ A0,
                                                   const float* __restrict__ A1,
                                                   int KSEG, int NSEG,
                                                   const float* __restrict__ B,
                                                   const float* __restrict__ bias,
                                                   float* __restrict__ C, int N) {
    gemm_body<ACT>(A0, A1, KSEG, NSEG, B, bias, C, N, blockIdx.y * 64, blockIdx.x * 64);
}

// ---------------------------------------------------------------------------
// Mega-kernel: level-1 of the DAG fused. Block ranges:
//   [0, G_GEMM1)            : X = hv @ w_gcn + b_gcn   (MFMA)
//   [+, G_PROJ)             : attention projections pu/pv/pe
//   [+, G_ZERO)             : zero dr/dc/acc
//   [+, G_IDX)              : one-hot index extraction (268 MB scan)
// ---------------------------------------------------------------------------
__global__ __launch_bounds__(256) void mega_kernel(
    const float* __restrict__ hv, const float* __restrict__ he,
    const float4* __restrict__ vew1, const float4* __restrict__ vew2,
    const float* __restrict__ watt,
    const float* __restrict__ wgcn, const float* __restrict__ bgcn,
    int* __restrict__ iu, int* __restrict__ iv,
    float* __restrict__ pu, float* __restrict__ pv, float* __restrict__ pe,
    float4* __restrict__ zbase, int zn4,
    float* __restrict__ X) {
    const int b = blockIdx.x;
    const int tid = threadIdx.x;

    if (b < G_GEMM1) {
        gemm_body<0>(hv, hv, HV, 1, wgcn, bgcn, X, HV, (b >> 2) * 64, (b & 3) * 64);
    } else if (b < G_GEMM1 + G_PROJ) {
        const int lane = tid & 63;
        for (int r = (b - G_GEMM1) * 4 + (tid >> 6); r < V + E; r += G_PROJ * 4) {
            if (r < V) {
                float4 x  = *(const float4*)(hv + (size_t)r * HV + lane * 4);
                float4 wu = *(const float4*)(watt + lane * 4);
                float4 wv = *(const float4*)(watt + HV + HE + lane * 4);
                float su = x.x * wu.x + x.y * wu.y + x.z * wu.z + x.w * wu.w;
                float sv = x.x * wv.x + x.y * wv.y + x.z * wv.z + x.w * wv.w;
                #pragma unroll
                for (int o = 32; o > 0; o >>= 1) {
                    su += __shfl_down(su, o);
                    sv += __shfl_down(sv, o);
                }
                if (lane == 0) { pu[r] = su; pv[r] = sv; }
            } else {
                int e = r - V;
                float2 x = *(const float2*)(he + (size_t)e * HE + lane * 2);
                float2 w = *(const float2*)(watt + HV + lane * 2);
                float s = x.x * w.x + x.y * w.y;
                #pragma unroll
                for (int o = 32; o > 0; o >>= 1) s += __shfl_down(s, o);
                if (lane == 0) pe[e] = s;
            }
        }
    } else if (b < G_GEMM1 + G_PROJ + G_ZERO) {
        float4 z = {0.0f, 0.0f, 0.0f, 0.0f};
        for (int i = (b - G_GEMM1 - G_PROJ) * 256 + tid; i < zn4; i += G_ZERO * 256)
            zbase[i] = z;
    } else {
        int ib = b - (G_GEMM1 + G_PROJ + G_ZERO);
        const float4* m = (ib < G_IDX / 2) ? vew1 : vew2;
        int* o = (ib < G_IDX / 2) ? iu : iv;
        ib &= (G_IDX / 2 - 1);
        size_t base = (size_t)ib * 2048 + tid;
        #pragma unroll
        for (int it = 0; it < 8; ++it) {
            size_t i = base + (size_t)it * 256;
            float4 x = m[i];
            if (x.x + x.y + x.z + x.w > 0.5f) {
                int v  = (int)(i >> 11);            // EQ = E/4 = 2048
                int c4 = ((int)i & 2047) << 2;
                if (x.x > 0.5f) o[c4 + 0] = v;
                if (x.y > 0.5f) o[c4 + 1] = v;
                if (x.z > 0.5f) o[c4 + 2] = v;
                if (x.w > 0.5f) o[c4 + 3] = v;
            }
        }
    }
}

// ---------------------------------------------------------------------------
// Edge weights + degrees (atomics).
// ---------------------------------------------------------------------------
__global__ __launch_bounds__(256) void edge_kernel(const int* __restrict__ iu,
                                                   const int* __restrict__ iv,
                                                   const float* __restrict__ pu,
                                                   const float* __restrict__ pv,
                                                   const float* __restrict__ pe,
                                                   const float* __restrict__ batt,
                                                   float* __restrict__ ew,
                                                   float* __restrict__ dr,
                                                   float* __restrict__ dc) {
    int e2 = blockIdx.x * blockDim.x + threadIdx.x;
    if (e2 >= 2 * E) return;
    int e  = (e2 < E) ? e2 : e2 - E;
    int uu = (e2 < E) ? iu[e] : iv[e];
    int vv = (e2 < E) ? iv[e] : iu[e];
    float x = pu[uu] + pe[e] + pv[vv] + batt[0];
    float w = 1.0f / (1.0f + expf(-x));
    ew[e2] = w;
    atomicAdd(dr + uu, w);
    atomicAdd(dc + vv, w);
}

// ---------------------------------------------------------------------------
// Scatter: acc[uu][:] += ew[e2] * dc^{-1/2}[vv] * X[vv][:]
// ---------------------------------------------------------------------------
__global__ __launch_bounds__(64) void scatter_kernel(const int* __restrict__ iu,
                                                     const int* __restrict__ iv,
                                                     const float* __restrict__ ew,
                                                     const float* __restrict__ dc,
                                                     const float* __restrict__ X,
                                                     float* __restrict__ acc) {
    int e2 = blockIdx.x;
    int t  = threadIdx.x;
    int e  = (e2 < E) ? e2 : e2 - E;
    int uu = (e2 < E) ? iu[e] : iv[e];
    int vv = (e2 < E) ? iv[e] : iu[e];
    float coef = ew[e2] * rsqrtf(fmaxf(dc[vv], EPS));
    float4 x = *(const float4*)(X + (size_t)vv * HV + t * 4);
    float* dst = acc + (size_t)uu * HV + t * 4;
    atomicAdd(dst + 0, coef * x.x);
    atomicAdd(dst + 1, coef * x.y);
    atomicAdd(dst + 2, coef * x.z);
    atomicAdd(dst + 3, coef * x.w);
}

// ---------------------------------------------------------------------------
// Finish GCN (in place, f32): acc = tanh(d_r^{-1/2}[row] * acc)
// ---------------------------------------------------------------------------
__global__ __launch_bounds__(256) void finish_kernel(const float* __restrict__ dr,
                                                     float4* __restrict__ acc) {
    int i = blockIdx.x * 256 + threadIdx.x;      // grid exactly V*HV/4 threads
    int row = i >> 6;                            // 64 float4 per 256-float row
    float s = rsqrtf(fmaxf(dr[row], EPS));
    float4 x = acc[i];
    x.x = tanhf(s * x.x); x.y = tanhf(s * x.y);
    x.z = tanhf(s * x.z); x.w = tanhf(s * x.w);
    acc[i] = x;
}

// ---------------------------------------------------------------------------
extern "C" void kernel_launch(void* const* d_in, const int* in_sizes, int n_in,
                              void* d_out, int out_size, void* d_ws, size_t ws_size,
                              hipStream_t stream) {
    const float* hv   = (const float*)d_in[0];
    const float* he   = (const float*)d_in[1];
    const float* vew1 = (const float*)d_in[2];
    const float* vew2 = (const float*)d_in[3];
    const float* watt = (const float*)d_in[4];
    const float* batt = (const float*)d_in[5];
    const float* wgcn = (const float*)d_in[6];
    const float* bgcn = (const float*)d_in[7];
    const float* w1   = (const float*)d_in[8];
    const float* b1   = (const float*)d_in[9];
    const float* w2   = (const float*)d_in[10];
    const float* b2   = (const float*)d_in[11];
    float* out = (float*)d_out;

    // workspace (all f32 words now -- no bf16 buffers)
    float* ws = (float*)d_ws;
    int*   iu  = (int*)ws;                       // E
    int*   iv  = (int*)(ws + E);                 // E
    float* pu  = ws + 2 * E;                     // V
    float* pv  = pu + V;                         // V
    float* pe  = pv + V;                         // E
    float* ew  = pe + E;                         // 2E
    float* dr  = ew + 2 * E;                     // V      (zeroed)
    float* dc  = dr + V;                         // V      (zeroed)
    float* acc = dc + V;                         // V*HV   (zeroed) -> hidden (in place)
    float* X   = acc + (size_t)V * HV;           // V*HV   (GCN linear out, later t)

    const int zn4 = (2 * V + V * HV) / 4;        // dr,dc,acc contiguous

    // level 1: idx scans + proj + gemm1 + zero, co-scheduled
    mega_kernel<<<G_TOTAL, 256, 0, stream>>>(hv, he, (const float4*)vew1,
        (const float4*)vew2, watt, wgcn, bgcn, iu, iv, pu, pv, pe,
        (float4*)dr, zn4, X);

    // level 2: edge weights + degrees
    edge_kernel<<<(2 * E + 255) / 256, 256, 0, stream>>>(iu, iv, pu, pv, pe, batt, ew, dr, dc);

    // level 3: scatter acc[uu] += ew * dc^{-1/2}[vv] * X[vv]
    scatter_kernel<<<2 * E, 64, 0, stream>>>(iu, iv, ew, dc, X, acc);

    // level 4: hidden = tanh(dr^{-1/2} * acc) in place
    finish_kernel<<<V * HV / 4 / 256, 256, 0, stream>>>(dr, (float4*)acc);

    // level 5: t = leaky_relu([hv | hidden] @ w1 + b1)  (K=512, two A segments, f32 out to X)
    gemm_kernel<1><<<dim3(HV / 64, V / 64), 256, 0, stream>>>(hv, acc, HV, 2, w1, b1, X, HV);

    // level 6: out = t @ w2 + b2
    gemm_kernel<0><<<dim3(OUT_DIM / 64, V / 64), 256, 0, stream>>>(X, X, HV, 1, w2, b2, out, OUT_DIM);
}